// Round 1
// baseline (535.988 us; speedup 1.0000x reference)
//
#include <hip/hip_runtime.h>
#include <math.h>

#define N_NODES 50000
#define N_EDGES 800000
#define F_IN    64
#define H_DIM   128
#define N_GRAPH 512
#define NEG_SLOPE 0.2f

// ---------------------------------------------------------------- CSR build
__global__ __launch_bounds__(256) void k_hist(const int* __restrict__ dst,
                                              int* __restrict__ counts) {
    int e = blockIdx.x * 256 + threadIdx.x;
    if (e < N_EDGES) atomicAdd(&counts[dst[e]], 1);
}

__global__ __launch_bounds__(256) void k_scan1(const int* __restrict__ counts,
                                               int* __restrict__ excl,
                                               int* __restrict__ partials) {
    __shared__ int s[256];
    int t = threadIdx.x, gid = blockIdx.x * 256 + t;
    int v = (gid < N_NODES) ? counts[gid] : 0;
    s[t] = v;
    __syncthreads();
    for (int off = 1; off < 256; off <<= 1) {
        int x = (t >= off) ? s[t - off] : 0;
        __syncthreads();
        s[t] += x;
        __syncthreads();
    }
    if (gid < N_NODES) excl[gid] = s[t] - v;   // exclusive within block
    if (t == 255) partials[blockIdx.x] = s[t]; // block total
}

__global__ __launch_bounds__(256) void k_scan2(int* __restrict__ partials, int nb) {
    __shared__ int s[256];
    int t = threadIdx.x;
    int v = (t < nb) ? partials[t] : 0;
    s[t] = v;
    __syncthreads();
    for (int off = 1; off < 256; off <<= 1) {
        int x = (t >= off) ? s[t - off] : 0;
        __syncthreads();
        s[t] += x;
        __syncthreads();
    }
    if (t < nb) partials[t] = s[t] - v;        // exclusive
}

__global__ __launch_bounds__(256) void k_scan3(int* __restrict__ offsets,
                                               const int* __restrict__ partials,
                                               int* __restrict__ cursor) {
    int gid = blockIdx.x * 256 + threadIdx.x;
    if (gid < N_NODES) {
        int v = offsets[gid] + partials[blockIdx.x];
        offsets[gid] = v;
        cursor[gid]  = v;
    }
    if (gid == 0) offsets[N_NODES] = N_EDGES;
}

__global__ __launch_bounds__(256) void k_fill(const int* __restrict__ src,
                                              const int* __restrict__ dst,
                                              int* __restrict__ cursor,
                                              int* __restrict__ col_src) {
    int e = blockIdx.x * 256 + threadIdx.x;
    if (e < N_EDGES) {
        int pos = atomicAdd(&cursor[dst[e]], 1);
        col_src[pos] = src[e];
    }
}

// ---------------------------------------------------------------- dual GEMM
// C = X @ W + b for W in {Wl, Wr} chosen by blockIdx.y.  X: N x K, W: K x 128.
__global__ __launch_bounds__(256) void k_gemm_dual(
    const float* __restrict__ X,
    const float* __restrict__ Wl, const float* __restrict__ bl,
    const float* __restrict__ Wr, const float* __restrict__ br,
    float* __restrict__ OL, float* __restrict__ OR_, int K)
{
    const float* W  = blockIdx.y ? Wr : Wl;
    const float* bs = blockIdx.y ? br : bl;
    float*       O  = blockIdx.y ? OR_ : OL;

    __shared__ float Xs[64 * 32];
    __shared__ float Ws[32 * 128];

    const int tid = threadIdx.x;
    const int tx = tid & 31, ty = tid >> 5;
    const int row0 = blockIdx.x * 64;

    float acc[8][4];
#pragma unroll
    for (int r = 0; r < 8; ++r)
#pragma unroll
        for (int c = 0; c < 4; ++c) acc[r][c] = 0.f;

    for (int kk = 0; kk < K; kk += 32) {
        // stage X tile (64 rows x 32 cols)
        for (int j = tid; j < 512; j += 256) {
            int r = j >> 3, c4 = (j & 7) << 2;
            int grow = row0 + r;
            float4 v = make_float4(0.f, 0.f, 0.f, 0.f);
            if (grow < N_NODES)
                v = *(const float4*)(X + (size_t)grow * K + kk + c4);
            *(float4*)(Xs + r * 32 + c4) = v;
        }
        // stage W tile (32 rows x 128 cols)
        for (int j = tid; j < 1024; j += 256) {
            int r = j >> 5, c4 = (j & 31) << 2;
            float4 v = *(const float4*)(W + (size_t)(kk + r) * 128 + c4);
            *(float4*)(Ws + r * 128 + c4) = v;
        }
        __syncthreads();
#pragma unroll 8
        for (int k = 0; k < 32; ++k) {
            float4 b = *(const float4*)(Ws + k * 128 + tx * 4);
#pragma unroll
            for (int r = 0; r < 8; ++r) {
                float a = Xs[(r * 8 + ty) * 32 + k];
                acc[r][0] = fmaf(a, b.x, acc[r][0]);
                acc[r][1] = fmaf(a, b.y, acc[r][1]);
                acc[r][2] = fmaf(a, b.z, acc[r][2]);
                acc[r][3] = fmaf(a, b.w, acc[r][3]);
            }
        }
        __syncthreads();
    }
    float4 bb = *(const float4*)(bs + tx * 4);
#pragma unroll
    for (int r = 0; r < 8; ++r) {
        int grow = row0 + r * 8 + ty;
        if (grow < N_NODES) {
            float4 o;
            o.x = acc[r][0] + bb.x;
            o.y = acc[r][1] + bb.y;
            o.z = acc[r][2] + bb.z;
            o.w = acc[r][3] + bb.w;
            *(float4*)(O + (size_t)grow * 128 + tx * 4) = o;
        }
    }
}

// ---------------------------------------------------------------- edge phase
__device__ __forceinline__ float waveAllSum(float v) {
#pragma unroll
    for (int off = 32; off > 0; off >>= 1) v += __shfl_xor(v, off);
    return v;
}

// one wave per destination node; online softmax over its incoming edges
__global__ __launch_bounds__(256) void k_edge(
    const float* __restrict__ xl, const float* __restrict__ xr,
    const float* __restrict__ att, const float* __restrict__ bias,
    const int* __restrict__ offsets, const int* __restrict__ col_src,
    float* __restrict__ out)
{
    int d = blockIdx.x * 4 + (threadIdx.x >> 6);
    if (d >= N_NODES) return;
    int lane = threadIdx.x & 63;

    const float2 xrv = *(const float2*)(xr + (size_t)d * 128 + lane * 2);
    const float2 av  = *(const float2*)(att + lane * 2);

    // self edge (reference always appends self loops)
    float2 xs = *(const float2*)(xl + (size_t)d * 128 + lane * 2);
    float e0 = xs.x + xrv.x, e1 = xs.y + xrv.y;
    float l0 = e0 > 0.f ? e0 : NEG_SLOPE * e0;
    float l1 = e1 > 0.f ? e1 : NEG_SLOPE * e1;
    float m    = waveAllSum(av.x * l0 + av.y * l1);
    float lsum = 1.f;
    float acc0 = xs.x, acc1 = xs.y;

    int ibeg = offsets[d], iend = offsets[d + 1];
    for (int i = ibeg; i < iend; ++i) {
        int s = col_src[i];
        float2 xv = *(const float2*)(xl + (size_t)s * 128 + lane * 2);
        e0 = xv.x + xrv.x; e1 = xv.y + xrv.y;
        l0 = e0 > 0.f ? e0 : NEG_SLOPE * e0;
        l1 = e1 > 0.f ? e1 : NEG_SLOPE * e1;
        float logit = waveAllSum(av.x * l0 + av.y * l1);
        float nm = fmaxf(m, logit);
        float sc = __expf(m - nm);
        float w  = __expf(logit - nm);
        lsum = lsum * sc + w;
        acc0 = acc0 * sc + w * xv.x;
        acc1 = acc1 * sc + w * xv.y;
        m = nm;
    }
    float inv = 1.f / lsum;
    float o0 = fmaxf(fmaf(acc0, inv, bias[lane * 2]),     0.f); // + bias, relu
    float o1 = fmaxf(fmaf(acc1, inv, bias[lane * 2 + 1]), 0.f);
    *(float2*)(out + (size_t)d * 128 + lane * 2) = make_float2(o0, o1);
}

// ---------------------------------------------------------------- pooling
__global__ __launch_bounds__(128) void k_pool(
    const float* __restrict__ h, const int* __restrict__ batch,
    float* __restrict__ psum, float* __restrict__ pcnt)
{
    int dim = threadIdx.x;
    int n0 = blockIdx.x * 128;
    int nend = n0 + 128; if (nend > N_NODES) nend = N_NODES;
    float accv = 0.f;
    int cur = -1, crun = 0;
    for (int n = n0; n < nend; ++n) {
        int g = batch[n];
        if (g != cur) {
            if (cur >= 0) {
                atomicAdd(&psum[cur * 128 + dim], accv);
                if (dim == 0) atomicAdd(&pcnt[cur], (float)crun);
            }
            cur = g; accv = 0.f; crun = 0;
        }
        accv += h[(size_t)n * 128 + dim];
        crun++;
    }
    if (cur >= 0) {
        atomicAdd(&psum[cur * 128 + dim], accv);
        if (dim == 0) atomicAdd(&pcnt[cur], (float)crun);
    }
}

__global__ __launch_bounds__(256) void k_head(
    const float* __restrict__ psum, const float* __restrict__ pcnt,
    const float* __restrict__ Wlin, const float* __restrict__ blin,
    float* __restrict__ out)
{
    int g = blockIdx.x * 4 + (threadIdx.x >> 6);
    if (g >= N_GRAPH) return;
    int lane = threadIdx.x & 63;
    float c = fmaxf(pcnt[g], 1.f);
    float2 s = *(const float2*)(psum + (size_t)g * 128 + lane * 2);
    float p = (s.x * Wlin[lane * 2] + s.y * Wlin[lane * 2 + 1]) / c;
    p = waveAllSum(p);
    if (lane == 0) out[g] = p + blin[0];
}

// ---------------------------------------------------------------- launch
extern "C" void kernel_launch(void* const* d_in, const int* in_sizes, int n_in,
                              void* d_out, int out_size, void* d_ws, size_t ws_size,
                              hipStream_t stream) {
    const float* x     = (const float*)d_in[0];
    const int*   ei    = (const int*)d_in[1];
    const int*   batch = (const int*)d_in[3];
    const float* Wl1 = (const float*)d_in[4],  *bl1 = (const float*)d_in[5];
    const float* Wr1 = (const float*)d_in[6],  *br1 = (const float*)d_in[7];
    const float* att1= (const float*)d_in[8],  *b1  = (const float*)d_in[9];
    const float* Wl2 = (const float*)d_in[10], *bl2 = (const float*)d_in[11];
    const float* Wr2 = (const float*)d_in[12], *br2 = (const float*)d_in[13];
    const float* att2= (const float*)d_in[14], *b2  = (const float*)d_in[15];
    const float* Wlin= (const float*)d_in[16], *blin= (const float*)d_in[17];
    float* out = (float*)d_out;

    const int* src = ei;             // edge_index[0]
    const int* dst = ei + N_EDGES;   // edge_index[1]

    // workspace carve (256B aligned)
    char* p = (char*)d_ws;
    auto carve = [&](size_t bytes) {
        void* r = (void*)p;
        p += (bytes + 255) & ~(size_t)255;
        return r;
    };
    float* bufA    = (float*)carve((size_t)N_NODES * 128 * 4); // xl
    float* bufB    = (float*)carve((size_t)N_NODES * 128 * 4); // xr
    float* bufC    = (float*)carve((size_t)N_NODES * 128 * 4); // h / h2
    int*   counts  = (int*)carve((size_t)N_NODES * 4);
    int*   offsets = (int*)carve((size_t)(N_NODES + 1) * 4);
    int*   cursor  = (int*)carve((size_t)N_NODES * 4);
    int*   partials= (int*)carve(256 * 4);
    int*   col_src = (int*)carve((size_t)N_EDGES * 4);
    float* psum    = (float*)carve((size_t)N_GRAPH * 128 * 4);
    float* pcnt    = (float*)carve((size_t)N_GRAPH * 4);

    hipMemsetAsync(counts, 0, (size_t)N_NODES * 4, stream);
    hipMemsetAsync(psum,   0, (size_t)N_GRAPH * 128 * 4, stream);
    hipMemsetAsync(pcnt,   0, (size_t)N_GRAPH * 4, stream);

    const int NB1 = (N_NODES + 255) / 256;   // 196
    k_hist <<<(N_EDGES + 255) / 256, 256, 0, stream>>>(dst, counts);
    k_scan1<<<NB1, 256, 0, stream>>>(counts, offsets, partials);
    k_scan2<<<1, 256, 0, stream>>>(partials, NB1);
    k_scan3<<<NB1, 256, 0, stream>>>(offsets, partials, cursor);
    k_fill <<<(N_EDGES + 255) / 256, 256, 0, stream>>>(src, dst, cursor, col_src);

    dim3 gg((N_NODES + 63) / 64, 2);
    // layer 1
    k_gemm_dual<<<gg, 256, 0, stream>>>(x, Wl1, bl1, Wr1, br1, bufA, bufB, F_IN);
    k_edge<<<(N_NODES + 3) / 4, 256, 0, stream>>>(bufA, bufB, att1, b1, offsets, col_src, bufC);
    // layer 2
    k_gemm_dual<<<gg, 256, 0, stream>>>(bufC, Wl2, bl2, Wr2, br2, bufA, bufB, H_DIM);
    k_edge<<<(N_NODES + 3) / 4, 256, 0, stream>>>(bufA, bufB, att2, b2, offsets, col_src, bufC);
    // pool + head
    k_pool<<<(N_NODES + 127) / 128, 128, 0, stream>>>(bufC, batch, psum, pcnt);
    k_head<<<(N_GRAPH + 3) / 4, 256, 0, stream>>>(psum, pcnt, Wlin, blin, out);
}

// Round 2
// 437.949 us; speedup vs baseline: 1.2239x; 1.2239x over previous
//
#include <hip/hip_runtime.h>
#include <math.h>

#define N_NODES 50000
#define N_EDGES 800000
#define F_IN    64
#define H_DIM   128
#define N_GRAPH 512
#define NEG_SLOPE 0.2f

// ---------------------------------------------------------------- CSR build
__global__ __launch_bounds__(256) void k_hist(const int* __restrict__ dst,
                                              int* __restrict__ counts) {
    int e = blockIdx.x * 256 + threadIdx.x;
    if (e < N_EDGES) atomicAdd(&counts[dst[e]], 1);
}

__global__ __launch_bounds__(256) void k_scan1(const int* __restrict__ counts,
                                               int* __restrict__ excl,
                                               int* __restrict__ partials) {
    __shared__ int s[256];
    int t = threadIdx.x, gid = blockIdx.x * 256 + t;
    int v = (gid < N_NODES) ? counts[gid] : 0;
    s[t] = v;
    __syncthreads();
    for (int off = 1; off < 256; off <<= 1) {
        int x = (t >= off) ? s[t - off] : 0;
        __syncthreads();
        s[t] += x;
        __syncthreads();
    }
    if (gid < N_NODES) excl[gid] = s[t] - v;   // exclusive within block
    if (t == 255) partials[blockIdx.x] = s[t]; // block total
}

__global__ __launch_bounds__(256) void k_scan2(int* __restrict__ partials, int nb) {
    __shared__ int s[256];
    int t = threadIdx.x;
    int v = (t < nb) ? partials[t] : 0;
    s[t] = v;
    __syncthreads();
    for (int off = 1; off < 256; off <<= 1) {
        int x = (t >= off) ? s[t - off] : 0;
        __syncthreads();
        s[t] += x;
        __syncthreads();
    }
    if (t < nb) partials[t] = s[t] - v;        // exclusive
}

__global__ __launch_bounds__(256) void k_scan3(int* __restrict__ offsets,
                                               const int* __restrict__ partials,
                                               int* __restrict__ cursor) {
    int gid = blockIdx.x * 256 + threadIdx.x;
    if (gid < N_NODES) {
        int v = offsets[gid] + partials[blockIdx.x];
        offsets[gid] = v;
        cursor[gid]  = v;
    }
    if (gid == 0) offsets[N_NODES] = N_EDGES;
}

__global__ __launch_bounds__(256) void k_fill(const int* __restrict__ src,
                                              const int* __restrict__ dst,
                                              int* __restrict__ cursor,
                                              int* __restrict__ col_src) {
    int e = blockIdx.x * 256 + threadIdx.x;
    if (e < N_EDGES) {
        int pos = atomicAdd(&cursor[dst[e]], 1);
        col_src[pos] = src[e];
    }
}

// ---------------------------------------------------------------- dual GEMM
// C = X @ W + b for W in {Wl, Wr} chosen by blockIdx.y.  X: N x K, W: K x 128.
__global__ __launch_bounds__(256) void k_gemm_dual(
    const float* __restrict__ X,
    const float* __restrict__ Wl, const float* __restrict__ bl,
    const float* __restrict__ Wr, const float* __restrict__ br,
    float* __restrict__ OL, float* __restrict__ OR_, int K)
{
    const float* W  = blockIdx.y ? Wr : Wl;
    const float* bs = blockIdx.y ? br : bl;
    float*       O  = blockIdx.y ? OR_ : OL;

    __shared__ float Xs[64 * 32];
    __shared__ float Ws[32 * 128];

    const int tid = threadIdx.x;
    const int tx = tid & 31, ty = tid >> 5;
    const int row0 = blockIdx.x * 64;

    float acc[8][4];
#pragma unroll
    for (int r = 0; r < 8; ++r)
#pragma unroll
        for (int c = 0; c < 4; ++c) acc[r][c] = 0.f;

    for (int kk = 0; kk < K; kk += 32) {
        // stage X tile (64 rows x 32 cols)
        for (int j = tid; j < 512; j += 256) {
            int r = j >> 3, c4 = (j & 7) << 2;
            int grow = row0 + r;
            float4 v = make_float4(0.f, 0.f, 0.f, 0.f);
            if (grow < N_NODES)
                v = *(const float4*)(X + (size_t)grow * K + kk + c4);
            *(float4*)(Xs + r * 32 + c4) = v;
        }
        // stage W tile (32 rows x 128 cols)
        for (int j = tid; j < 1024; j += 256) {
            int r = j >> 5, c4 = (j & 31) << 2;
            float4 v = *(const float4*)(W + (size_t)(kk + r) * 128 + c4);
            *(float4*)(Ws + r * 128 + c4) = v;
        }
        __syncthreads();
#pragma unroll 8
        for (int k = 0; k < 32; ++k) {
            float4 b = *(const float4*)(Ws + k * 128 + tx * 4);
#pragma unroll
            for (int r = 0; r < 8; ++r) {
                float a = Xs[(r * 8 + ty) * 32 + k];
                acc[r][0] = fmaf(a, b.x, acc[r][0]);
                acc[r][1] = fmaf(a, b.y, acc[r][1]);
                acc[r][2] = fmaf(a, b.z, acc[r][2]);
                acc[r][3] = fmaf(a, b.w, acc[r][3]);
            }
        }
        __syncthreads();
    }
    float4 bb = *(const float4*)(bs + tx * 4);
#pragma unroll
    for (int r = 0; r < 8; ++r) {
        int grow = row0 + r * 8 + ty;
        if (grow < N_NODES) {
            float4 o;
            o.x = acc[r][0] + bb.x;
            o.y = acc[r][1] + bb.y;
            o.z = acc[r][2] + bb.z;
            o.w = acc[r][3] + bb.w;
            *(float4*)(O + (size_t)grow * 128 + tx * 4) = o;
        }
    }
}

// ---------------------------------------------------------------- edge phase
__device__ __forceinline__ float dot8_leaky(const float4& x0, const float4& x1,
                                            const float4& r0, const float4& r1,
                                            const float4& a0, const float4& a1) {
    float s = 0.f, e;
    e = x0.x + r0.x; s = fmaf(a0.x, (e > 0.f ? e : NEG_SLOPE * e), s);
    e = x0.y + r0.y; s = fmaf(a0.y, (e > 0.f ? e : NEG_SLOPE * e), s);
    e = x0.z + r0.z; s = fmaf(a0.z, (e > 0.f ? e : NEG_SLOPE * e), s);
    e = x0.w + r0.w; s = fmaf(a0.w, (e > 0.f ? e : NEG_SLOPE * e), s);
    e = x1.x + r1.x; s = fmaf(a1.x, (e > 0.f ? e : NEG_SLOPE * e), s);
    e = x1.y + r1.y; s = fmaf(a1.y, (e > 0.f ? e : NEG_SLOPE * e), s);
    e = x1.z + r1.z; s = fmaf(a1.z, (e > 0.f ? e : NEG_SLOPE * e), s);
    e = x1.w + r1.w; s = fmaf(a1.w, (e > 0.f ? e : NEG_SLOPE * e), s);
    return s;
}

// One wave per destination node. The wave is split into 4 quarters of 16
// lanes; each quarter processes a different incoming edge concurrently
// (4+ loads in flight -> latency hiding). Lane (q,t) covers dims
// [t*8, t*8+8). Each quarter keeps a private online-softmax state,
// merged across quarters once at the end via shfl_xor(16/32).
__global__ __launch_bounds__(256) void k_edge(
    const float* __restrict__ xl, const float* __restrict__ xr,
    const float* __restrict__ att, const float* __restrict__ bias,
    const int* __restrict__ offsets, const int* __restrict__ col_src,
    float* __restrict__ out)
{
    int d = blockIdx.x * 4 + (threadIdx.x >> 6);
    if (d >= N_NODES) return;
    const int lane = threadIdx.x & 63;
    const int q = lane >> 4;      // quarter 0..3
    const int t = lane & 15;      // sublane 0..15; dims [t*8, t*8+8)
    const size_t dim0 = (size_t)t * 8;

    const float4 r0 = *(const float4*)(xr + (size_t)d * 128 + dim0);
    const float4 r1 = *(const float4*)(xr + (size_t)d * 128 + dim0 + 4);
    const float4 a0 = *(const float4*)(att + dim0);
    const float4 a1 = *(const float4*)(att + dim0 + 4);

    // self edge (reference appends self loops): quarter 0 only
    const float4 xs0 = *(const float4*)(xl + (size_t)d * 128 + dim0);
    const float4 xs1 = *(const float4*)(xl + (size_t)d * 128 + dim0 + 4);
    float sl = dot8_leaky(xs0, xs1, r0, r1, a0, a1);
#pragma unroll
    for (int off = 1; off < 16; off <<= 1) sl += __shfl_xor(sl, off);

    float m, lsum;
    float4 acc0, acc1;
    if (q == 0) {
        m = sl; lsum = 1.f; acc0 = xs0; acc1 = xs1;
    } else {
        m = -INFINITY; lsum = 0.f;
        acc0 = make_float4(0.f, 0.f, 0.f, 0.f);
        acc1 = make_float4(0.f, 0.f, 0.f, 0.f);
    }

    const int ibeg = offsets[d], iend = offsets[d + 1];
    for (int base = ibeg; base < iend; base += 4) {
        int i = base + q;
        bool valid = (i < iend);
        int s = valid ? col_src[i] : d;
        const float4 x0 = *(const float4*)(xl + (size_t)s * 128 + dim0);
        const float4 x1 = *(const float4*)(xl + (size_t)s * 128 + dim0 + 4);
        float logit = dot8_leaky(x0, x1, r0, r1, a0, a1);
#pragma unroll
        for (int off = 1; off < 16; off <<= 1) logit += __shfl_xor(logit, off);
        if (valid) {
            float nm = fmaxf(m, logit);
            float sc = __expf(m - nm);       // m may be -inf -> 0
            float w  = __expf(logit - nm);
            lsum = lsum * sc + w;
            acc0.x = acc0.x * sc + w * x0.x;
            acc0.y = acc0.y * sc + w * x0.y;
            acc0.z = acc0.z * sc + w * x0.z;
            acc0.w = acc0.w * sc + w * x0.w;
            acc1.x = acc1.x * sc + w * x1.x;
            acc1.y = acc1.y * sc + w * x1.y;
            acc1.z = acc1.z * sc + w * x1.z;
            acc1.w = acc1.w * sc + w * x1.w;
            m = nm;
        }
    }

    // merge quarters: global max, rescale, sum
    float M = m;
    M = fmaxf(M, __shfl_xor(M, 16));
    M = fmaxf(M, __shfl_xor(M, 32));
    float sc = __expf(m - M);                 // m=-inf -> 0
    lsum *= sc;
    acc0.x *= sc; acc0.y *= sc; acc0.z *= sc; acc0.w *= sc;
    acc1.x *= sc; acc1.y *= sc; acc1.z *= sc; acc1.w *= sc;
#pragma unroll
    for (int off = 16; off <= 32; off <<= 1) {
        lsum  += __shfl_xor(lsum, off);
        acc0.x += __shfl_xor(acc0.x, off);
        acc0.y += __shfl_xor(acc0.y, off);
        acc0.z += __shfl_xor(acc0.z, off);
        acc0.w += __shfl_xor(acc0.w, off);
        acc1.x += __shfl_xor(acc1.x, off);
        acc1.y += __shfl_xor(acc1.y, off);
        acc1.z += __shfl_xor(acc1.z, off);
        acc1.w += __shfl_xor(acc1.w, off);
    }

    if (q == 0) {
        float inv = 1.f / lsum;
        const float4 b0 = *(const float4*)(bias + dim0);
        const float4 b1 = *(const float4*)(bias + dim0 + 4);
        float4 o0, o1;
        o0.x = fmaxf(fmaf(acc0.x, inv, b0.x), 0.f);
        o0.y = fmaxf(fmaf(acc0.y, inv, b0.y), 0.f);
        o0.z = fmaxf(fmaf(acc0.z, inv, b0.z), 0.f);
        o0.w = fmaxf(fmaf(acc0.w, inv, b0.w), 0.f);
        o1.x = fmaxf(fmaf(acc1.x, inv, b1.x), 0.f);
        o1.y = fmaxf(fmaf(acc1.y, inv, b1.y), 0.f);
        o1.z = fmaxf(fmaf(acc1.z, inv, b1.z), 0.f);
        o1.w = fmaxf(fmaf(acc1.w, inv, b1.w), 0.f);
        *(float4*)(out + (size_t)d * 128 + dim0)     = o0;
        *(float4*)(out + (size_t)d * 128 + dim0 + 4) = o1;
    }
}

// ---------------------------------------------------------------- pooling
__global__ __launch_bounds__(128) void k_pool(
    const float* __restrict__ h, const int* __restrict__ batch,
    float* __restrict__ psum, float* __restrict__ pcnt)
{
    int dim = threadIdx.x;
    int n0 = blockIdx.x * 128;
    int nend = n0 + 128; if (nend > N_NODES) nend = N_NODES;
    float accv = 0.f;
    int cur = -1, crun = 0;
    for (int n = n0; n < nend; ++n) {
        int g = batch[n];
        if (g != cur) {
            if (cur >= 0) {
                atomicAdd(&psum[cur * 128 + dim], accv);
                if (dim == 0) atomicAdd(&pcnt[cur], (float)crun);
            }
            cur = g; accv = 0.f; crun = 0;
        }
        accv += h[(size_t)n * 128 + dim];
        crun++;
    }
    if (cur >= 0) {
        atomicAdd(&psum[cur * 128 + dim], accv);
        if (dim == 0) atomicAdd(&pcnt[cur], (float)crun);
    }
}

__global__ __launch_bounds__(256) void k_head(
    const float* __restrict__ psum, const float* __restrict__ pcnt,
    const float* __restrict__ Wlin, const float* __restrict__ blin,
    float* __restrict__ out)
{
    int g = blockIdx.x * 4 + (threadIdx.x >> 6);
    if (g >= N_GRAPH) return;
    int lane = threadIdx.x & 63;
    float c = fmaxf(pcnt[g], 1.f);
    float2 s = *(const float2*)(psum + (size_t)g * 128 + lane * 2);
    float p = (s.x * Wlin[lane * 2] + s.y * Wlin[lane * 2 + 1]) / c;
#pragma unroll
    for (int off = 32; off > 0; off >>= 1) p += __shfl_xor(p, off);
    if (lane == 0) out[g] = p + blin[0];
}

// ---------------------------------------------------------------- launch
extern "C" void kernel_launch(void* const* d_in, const int* in_sizes, int n_in,
                              void* d_out, int out_size, void* d_ws, size_t ws_size,
                              hipStream_t stream) {
    const float* x     = (const float*)d_in[0];
    const int*   ei    = (const int*)d_in[1];
    const int*   batch = (const int*)d_in[3];
    const float* Wl1 = (const float*)d_in[4],  *bl1 = (const float*)d_in[5];
    const float* Wr1 = (const float*)d_in[6],  *br1 = (const float*)d_in[7];
    const float* att1= (const float*)d_in[8],  *b1  = (const float*)d_in[9];
    const float* Wl2 = (const float*)d_in[10], *bl2 = (const float*)d_in[11];
    const float* Wr2 = (const float*)d_in[12], *br2 = (const float*)d_in[13];
    const float* att2= (const float*)d_in[14], *b2  = (const float*)d_in[15];
    const float* Wlin= (const float*)d_in[16], *blin= (const float*)d_in[17];
    float* out = (float*)d_out;

    const int* src = ei;             // edge_index[0]
    const int* dst = ei + N_EDGES;   // edge_index[1]

    // workspace carve (256B aligned)
    char* p = (char*)d_ws;
    auto carve = [&](size_t bytes) {
        void* r = (void*)p;
        p += (bytes + 255) & ~(size_t)255;
        return r;
    };
    float* bufA    = (float*)carve((size_t)N_NODES * 128 * 4); // xl
    float* bufB    = (float*)carve((size_t)N_NODES * 128 * 4); // xr
    float* bufC    = (float*)carve((size_t)N_NODES * 128 * 4); // h / h2
    int*   counts  = (int*)carve((size_t)N_NODES * 4);
    int*   offsets = (int*)carve((size_t)(N_NODES + 1) * 4);
    int*   cursor  = (int*)carve((size_t)N_NODES * 4);
    int*   partials= (int*)carve(256 * 4);
    int*   col_src = (int*)carve((size_t)N_EDGES * 4);
    float* psum    = (float*)carve((size_t)N_GRAPH * 128 * 4);
    float* pcnt    = (float*)carve((size_t)N_GRAPH * 4);

    hipMemsetAsync(counts, 0, (size_t)N_NODES * 4, stream);
    hipMemsetAsync(psum,   0, (size_t)N_GRAPH * 128 * 4, stream);
    hipMemsetAsync(pcnt,   0, (size_t)N_GRAPH * 4, stream);

    const int NB1 = (N_NODES + 255) / 256;   // 196
    k_hist <<<(N_EDGES + 255) / 256, 256, 0, stream>>>(dst, counts);
    k_scan1<<<NB1, 256, 0, stream>>>(counts, offsets, partials);
    k_scan2<<<1, 256, 0, stream>>>(partials, NB1);
    k_scan3<<<NB1, 256, 0, stream>>>(offsets, partials, cursor);
    k_fill <<<(N_EDGES + 255) / 256, 256, 0, stream>>>(src, dst, cursor, col_src);

    dim3 gg((N_NODES + 63) / 64, 2);
    // layer 1
    k_gemm_dual<<<gg, 256, 0, stream>>>(x, Wl1, bl1, Wr1, br1, bufA, bufB, F_IN);
    k_edge<<<(N_NODES + 3) / 4, 256, 0, stream>>>(bufA, bufB, att1, b1, offsets, col_src, bufC);
    // layer 2
    k_gemm_dual<<<gg, 256, 0, stream>>>(bufC, Wl2, bl2, Wr2, br2, bufA, bufB, H_DIM);
    k_edge<<<(N_NODES + 3) / 4, 256, 0, stream>>>(bufA, bufB, att2, b2, offsets, col_src, bufC);
    // pool + head
    k_pool<<<(N_NODES + 127) / 128, 128, 0, stream>>>(bufC, batch, psum, pcnt);
    k_head<<<(N_GRAPH + 3) / 4, 256, 0, stream>>>(psum, pcnt, Wlin, blin, out);
}

// Round 3
// 433.449 us; speedup vs baseline: 1.2366x; 1.0104x over previous
//
#include <hip/hip_runtime.h>
#include <math.h>

#define N_NODES 50000
#define N_EDGES 800000
#define F_IN    64
#define H_DIM   128
#define N_GRAPH 512
#define NEG_SLOPE 0.2f

// ---------------------------------------------------------------- CSR build
__global__ __launch_bounds__(256) void k_hist(const int* __restrict__ dst,
                                              int* __restrict__ counts) {
    int e = blockIdx.x * 256 + threadIdx.x;
    if (e < N_EDGES) atomicAdd(&counts[dst[e]], 1);
}

__global__ __launch_bounds__(256) void k_scan1(const int* __restrict__ counts,
                                               int* __restrict__ excl,
                                               int* __restrict__ partials) {
    __shared__ int s[256];
    int t = threadIdx.x, gid = blockIdx.x * 256 + t;
    int v = (gid < N_NODES) ? counts[gid] : 0;
    s[t] = v;
    __syncthreads();
    for (int off = 1; off < 256; off <<= 1) {
        int x = (t >= off) ? s[t - off] : 0;
        __syncthreads();
        s[t] += x;
        __syncthreads();
    }
    if (gid < N_NODES) excl[gid] = s[t] - v;   // exclusive within block
    if (t == 255) partials[blockIdx.x] = s[t]; // block total
}

__global__ __launch_bounds__(256) void k_scan2(int* __restrict__ partials, int nb) {
    __shared__ int s[256];
    int t = threadIdx.x;
    int v = (t < nb) ? partials[t] : 0;
    s[t] = v;
    __syncthreads();
    for (int off = 1; off < 256; off <<= 1) {
        int x = (t >= off) ? s[t - off] : 0;
        __syncthreads();
        s[t] += x;
        __syncthreads();
    }
    if (t < nb) partials[t] = s[t] - v;        // exclusive
}

__global__ __launch_bounds__(256) void k_scan3(int* __restrict__ offsets,
                                               const int* __restrict__ partials,
                                               int* __restrict__ cursor) {
    int gid = blockIdx.x * 256 + threadIdx.x;
    if (gid < N_NODES) {
        int v = offsets[gid] + partials[blockIdx.x];
        offsets[gid] = v;
        cursor[gid]  = v;
    }
    if (gid == 0) offsets[N_NODES] = N_EDGES;
}

__global__ __launch_bounds__(256) void k_fill(const int* __restrict__ src,
                                              const int* __restrict__ dst,
                                              int* __restrict__ cursor,
                                              int* __restrict__ col_src) {
    int e = blockIdx.x * 256 + threadIdx.x;
    if (e < N_EDGES) {
        int pos = atomicAdd(&cursor[dst[e]], 1);
        col_src[pos] = src[e];
    }
}

// ---------------------------------------------------------------- dual GEMM
// C = X @ W + b for W in {Wl, Wr} chosen by blockIdx.y.  X: N x K, W: K x 128.
// 128x128 tile, 256 threads (16x16), 8x8 micro-tile, BK=32.
// A staged transposed in LDS (pitch 132 keeps 16B align); B cols split
// tx*4 / 64+tx*4 so ds_read_b128 covers all banks with <=2-way aliasing.
#define XPITCH 132
__global__ __launch_bounds__(256) void k_gemm_dual(
    const float* __restrict__ X,
    const float* __restrict__ Wl, const float* __restrict__ bl,
    const float* __restrict__ Wr, const float* __restrict__ br,
    float* __restrict__ OL, float* __restrict__ OR_, int K)
{
    const float* W  = blockIdx.y ? Wr : Wl;
    const float* bs = blockIdx.y ? br : bl;
    float*       O  = blockIdx.y ? OR_ : OL;

    __shared__ float XsT[32 * XPITCH];   // [k][row], 16.9 KB
    __shared__ float Ws[32 * 128];       // [k][col], 16.4 KB

    const int tid = threadIdx.x;
    const int tx = tid & 15;             // col group
    const int ty = tid >> 4;             // row group
    const int row0 = blockIdx.x * 128;

    float acc[8][8];
#pragma unroll
    for (int i = 0; i < 8; ++i)
#pragma unroll
        for (int j = 0; j < 8; ++j) acc[i][j] = 0.f;

    for (int kk = 0; kk < K; kk += 32) {
        // stage X tile transposed: rows row0..+127, cols kk..kk+31
#pragma unroll
        for (int jj = 0; jj < 4; ++jj) {
            int j = tid + jj * 256;          // 0..1023
            int r = j >> 3;                  // 0..127
            int c4 = (j & 7) << 2;           // 0,4,...,28
            int grow = row0 + r;
            float4 v = make_float4(0.f, 0.f, 0.f, 0.f);
            if (grow < N_NODES)
                v = *(const float4*)(X + (size_t)grow * K + kk + c4);
            XsT[(c4 + 0) * XPITCH + r] = v.x;
            XsT[(c4 + 1) * XPITCH + r] = v.y;
            XsT[(c4 + 2) * XPITCH + r] = v.z;
            XsT[(c4 + 3) * XPITCH + r] = v.w;
        }
        // stage W tile: rows kk..kk+31, all 128 cols (row-major copy)
#pragma unroll
        for (int jj = 0; jj < 4; ++jj) {
            int j = tid + jj * 256;          // 0..1023
            int r = j >> 5;                  // 0..31
            int c4 = (j & 31) << 2;          // 0..124
            float4 v = *(const float4*)(W + (size_t)(kk + r) * 128 + c4);
            *(float4*)(Ws + r * 128 + c4) = v;
        }
        __syncthreads();
#pragma unroll 8
        for (int k = 0; k < 32; ++k) {
            float4 a0 = *(const float4*)(XsT + k * XPITCH + ty * 8);
            float4 a1 = *(const float4*)(XsT + k * XPITCH + ty * 8 + 4);
            float4 b0 = *(const float4*)(Ws + k * 128 + tx * 4);
            float4 b1 = *(const float4*)(Ws + k * 128 + 64 + tx * 4);
            float a_[8] = {a0.x, a0.y, a0.z, a0.w, a1.x, a1.y, a1.z, a1.w};
            float b_[8] = {b0.x, b0.y, b0.z, b0.w, b1.x, b1.y, b1.z, b1.w};
#pragma unroll
            for (int i = 0; i < 8; ++i)
#pragma unroll
                for (int j = 0; j < 8; ++j)
                    acc[i][j] = fmaf(a_[i], b_[j], acc[i][j]);
        }
        __syncthreads();
    }

    const float4 bb0 = *(const float4*)(bs + tx * 4);
    const float4 bb1 = *(const float4*)(bs + 64 + tx * 4);
#pragma unroll
    for (int i = 0; i < 8; ++i) {
        int grow = row0 + ty * 8 + i;
        if (grow < N_NODES) {
            float4 o0, o1;
            o0.x = acc[i][0] + bb0.x; o0.y = acc[i][1] + bb0.y;
            o0.z = acc[i][2] + bb0.z; o0.w = acc[i][3] + bb0.w;
            o1.x = acc[i][4] + bb1.x; o1.y = acc[i][5] + bb1.y;
            o1.z = acc[i][6] + bb1.z; o1.w = acc[i][7] + bb1.w;
            *(float4*)(O + (size_t)grow * 128 + tx * 4)      = o0;
            *(float4*)(O + (size_t)grow * 128 + 64 + tx * 4) = o1;
        }
    }
}

// ---------------------------------------------------------------- edge phase
__device__ __forceinline__ float dot8_leaky(const float4& x0, const float4& x1,
                                            const float4& r0, const float4& r1,
                                            const float4& a0, const float4& a1) {
    float s = 0.f, e;
    e = x0.x + r0.x; s = fmaf(a0.x, (e > 0.f ? e : NEG_SLOPE * e), s);
    e = x0.y + r0.y; s = fmaf(a0.y, (e > 0.f ? e : NEG_SLOPE * e), s);
    e = x0.z + r0.z; s = fmaf(a0.z, (e > 0.f ? e : NEG_SLOPE * e), s);
    e = x0.w + r0.w; s = fmaf(a0.w, (e > 0.f ? e : NEG_SLOPE * e), s);
    e = x1.x + r1.x; s = fmaf(a1.x, (e > 0.f ? e : NEG_SLOPE * e), s);
    e = x1.y + r1.y; s = fmaf(a1.y, (e > 0.f ? e : NEG_SLOPE * e), s);
    e = x1.z + r1.z; s = fmaf(a1.z, (e > 0.f ? e : NEG_SLOPE * e), s);
    e = x1.w + r1.w; s = fmaf(a1.w, (e > 0.f ? e : NEG_SLOPE * e), s);
    return s;
}

// One wave per destination node; 4 quarters of 16 lanes, each quarter
// processes a different incoming edge (online softmax, merged at the end).
__global__ __launch_bounds__(256) void k_edge(
    const float* __restrict__ xl, const float* __restrict__ xr,
    const float* __restrict__ att, const float* __restrict__ bias,
    const int* __restrict__ offsets, const int* __restrict__ col_src,
    float* __restrict__ out)
{
    int d = blockIdx.x * 4 + (threadIdx.x >> 6);
    if (d >= N_NODES) return;
    const int lane = threadIdx.x & 63;
    const int q = lane >> 4;      // quarter 0..3
    const int t = lane & 15;      // sublane 0..15; dims [t*8, t*8+8)
    const size_t dim0 = (size_t)t * 8;

    const float4 r0 = *(const float4*)(xr + (size_t)d * 128 + dim0);
    const float4 r1 = *(const float4*)(xr + (size_t)d * 128 + dim0 + 4);
    const float4 a0 = *(const float4*)(att + dim0);
    const float4 a1 = *(const float4*)(att + dim0 + 4);

    // self edge (reference appends self loops): quarter 0 only
    const float4 xs0 = *(const float4*)(xl + (size_t)d * 128 + dim0);
    const float4 xs1 = *(const float4*)(xl + (size_t)d * 128 + dim0 + 4);
    float sl = dot8_leaky(xs0, xs1, r0, r1, a0, a1);
#pragma unroll
    for (int off = 1; off < 16; off <<= 1) sl += __shfl_xor(sl, off);

    float m, lsum;
    float4 acc0, acc1;
    if (q == 0) {
        m = sl; lsum = 1.f; acc0 = xs0; acc1 = xs1;
    } else {
        m = -INFINITY; lsum = 0.f;
        acc0 = make_float4(0.f, 0.f, 0.f, 0.f);
        acc1 = make_float4(0.f, 0.f, 0.f, 0.f);
    }

    const int ibeg = offsets[d], iend = offsets[d + 1];
    for (int base = ibeg; base < iend; base += 4) {
        int i = base + q;
        bool valid = (i < iend);
        int s = valid ? col_src[i] : d;
        const float4 x0 = *(const float4*)(xl + (size_t)s * 128 + dim0);
        const float4 x1 = *(const float4*)(xl + (size_t)s * 128 + dim0 + 4);
        float logit = dot8_leaky(x0, x1, r0, r1, a0, a1);
#pragma unroll
        for (int off = 1; off < 16; off <<= 1) logit += __shfl_xor(logit, off);
        if (valid) {
            float nm = fmaxf(m, logit);
            float sc = __expf(m - nm);       // m may be -inf -> 0
            float w  = __expf(logit - nm);
            lsum = lsum * sc + w;
            acc0.x = acc0.x * sc + w * x0.x;
            acc0.y = acc0.y * sc + w * x0.y;
            acc0.z = acc0.z * sc + w * x0.z;
            acc0.w = acc0.w * sc + w * x0.w;
            acc1.x = acc1.x * sc + w * x1.x;
            acc1.y = acc1.y * sc + w * x1.y;
            acc1.z = acc1.z * sc + w * x1.z;
            acc1.w = acc1.w * sc + w * x1.w;
            m = nm;
        }
    }

    // merge quarters: global max, rescale, sum
    float M = m;
    M = fmaxf(M, __shfl_xor(M, 16));
    M = fmaxf(M, __shfl_xor(M, 32));
    float sc = __expf(m - M);                 // m=-inf -> 0
    lsum *= sc;
    acc0.x *= sc; acc0.y *= sc; acc0.z *= sc; acc0.w *= sc;
    acc1.x *= sc; acc1.y *= sc; acc1.z *= sc; acc1.w *= sc;
#pragma unroll
    for (int off = 16; off <= 32; off <<= 1) {
        lsum  += __shfl_xor(lsum, off);
        acc0.x += __shfl_xor(acc0.x, off);
        acc0.y += __shfl_xor(acc0.y, off);
        acc0.z += __shfl_xor(acc0.z, off);
        acc0.w += __shfl_xor(acc0.w, off);
        acc1.x += __shfl_xor(acc1.x, off);
        acc1.y += __shfl_xor(acc1.y, off);
        acc1.z += __shfl_xor(acc1.z, off);
        acc1.w += __shfl_xor(acc1.w, off);
    }

    if (q == 0) {
        float inv = 1.f / lsum;
        const float4 b0 = *(const float4*)(bias + dim0);
        const float4 b1 = *(const float4*)(bias + dim0 + 4);
        float4 o0, o1;
        o0.x = fmaxf(fmaf(acc0.x, inv, b0.x), 0.f);
        o0.y = fmaxf(fmaf(acc0.y, inv, b0.y), 0.f);
        o0.z = fmaxf(fmaf(acc0.z, inv, b0.z), 0.f);
        o0.w = fmaxf(fmaf(acc0.w, inv, b0.w), 0.f);
        o1.x = fmaxf(fmaf(acc1.x, inv, b1.x), 0.f);
        o1.y = fmaxf(fmaf(acc1.y, inv, b1.y), 0.f);
        o1.z = fmaxf(fmaf(acc1.z, inv, b1.z), 0.f);
        o1.w = fmaxf(fmaf(acc1.w, inv, b1.w), 0.f);
        *(float4*)(out + (size_t)d * 128 + dim0)     = o0;
        *(float4*)(out + (size_t)d * 128 + dim0 + 4) = o1;
    }
}

// ---------------------------------------------------------------- pooling
__global__ __launch_bounds__(128) void k_pool(
    const float* __restrict__ h, const int* __restrict__ batch,
    float* __restrict__ psum, float* __restrict__ pcnt)
{
    int dim = threadIdx.x;
    int n0 = blockIdx.x * 128;
    int nend = n0 + 128; if (nend > N_NODES) nend = N_NODES;
    float accv = 0.f;
    int cur = -1, crun = 0;
    for (int n = n0; n < nend; ++n) {
        int g = batch[n];
        if (g != cur) {
            if (cur >= 0) {
                atomicAdd(&psum[cur * 128 + dim], accv);
                if (dim == 0) atomicAdd(&pcnt[cur], (float)crun);
            }
            cur = g; accv = 0.f; crun = 0;
        }
        accv += h[(size_t)n * 128 + dim];
        crun++;
    }
    if (cur >= 0) {
        atomicAdd(&psum[cur * 128 + dim], accv);
        if (dim == 0) atomicAdd(&pcnt[cur], (float)crun);
    }
}

__global__ __launch_bounds__(256) void k_head(
    const float* __restrict__ psum, const float* __restrict__ pcnt,
    const float* __restrict__ Wlin, const float* __restrict__ blin,
    float* __restrict__ out)
{
    int g = blockIdx.x * 4 + (threadIdx.x >> 6);
    if (g >= N_GRAPH) return;
    int lane = threadIdx.x & 63;
    float c = fmaxf(pcnt[g], 1.f);
    float2 s = *(const float2*)(psum + (size_t)g * 128 + lane * 2);
    float p = (s.x * Wlin[lane * 2] + s.y * Wlin[lane * 2 + 1]) / c;
#pragma unroll
    for (int off = 32; off > 0; off >>= 1) p += __shfl_xor(p, off);
    if (lane == 0) out[g] = p + blin[0];
}

// ---------------------------------------------------------------- launch
extern "C" void kernel_launch(void* const* d_in, const int* in_sizes, int n_in,
                              void* d_out, int out_size, void* d_ws, size_t ws_size,
                              hipStream_t stream) {
    const float* x     = (const float*)d_in[0];
    const int*   ei    = (const int*)d_in[1];
    const int*   batch = (const int*)d_in[3];
    const float* Wl1 = (const float*)d_in[4],  *bl1 = (const float*)d_in[5];
    const float* Wr1 = (const float*)d_in[6],  *br1 = (const float*)d_in[7];
    const float* att1= (const float*)d_in[8],  *b1  = (const float*)d_in[9];
    const float* Wl2 = (const float*)d_in[10], *bl2 = (const float*)d_in[11];
    const float* Wr2 = (const float*)d_in[12], *br2 = (const float*)d_in[13];
    const float* att2= (const float*)d_in[14], *b2  = (const float*)d_in[15];
    const float* Wlin= (const float*)d_in[16], *blin= (const float*)d_in[17];
    float* out = (float*)d_out;

    const int* src = ei;             // edge_index[0]
    const int* dst = ei + N_EDGES;   // edge_index[1]

    // workspace carve (256B aligned)
    char* p = (char*)d_ws;
    auto carve = [&](size_t bytes) {
        void* r = (void*)p;
        p += (bytes + 255) & ~(size_t)255;
        return r;
    };
    float* bufA    = (float*)carve((size_t)N_NODES * 128 * 4); // xl
    float* bufB    = (float*)carve((size_t)N_NODES * 128 * 4); // xr
    float* bufC    = (float*)carve((size_t)N_NODES * 128 * 4); // h / h2
    int*   counts  = (int*)carve((size_t)N_NODES * 4);
    int*   offsets = (int*)carve((size_t)(N_NODES + 1) * 4);
    int*   cursor  = (int*)carve((size_t)N_NODES * 4);
    int*   partials= (int*)carve(256 * 4);
    int*   col_src = (int*)carve((size_t)N_EDGES * 4);
    float* psum    = (float*)carve((size_t)N_GRAPH * 128 * 4);
    float* pcnt    = (float*)carve((size_t)N_GRAPH * 4);

    hipMemsetAsync(counts, 0, (size_t)N_NODES * 4, stream);
    hipMemsetAsync(psum,   0, (size_t)N_GRAPH * 128 * 4, stream);
    hipMemsetAsync(pcnt,   0, (size_t)N_GRAPH * 4, stream);

    const int NB1 = (N_NODES + 255) / 256;   // 196
    k_hist <<<(N_EDGES + 255) / 256, 256, 0, stream>>>(dst, counts);
    k_scan1<<<NB1, 256, 0, stream>>>(counts, offsets, partials);
    k_scan2<<<1, 256, 0, stream>>>(partials, NB1);
    k_scan3<<<NB1, 256, 0, stream>>>(offsets, partials, cursor);
    k_fill <<<(N_EDGES + 255) / 256, 256, 0, stream>>>(src, dst, cursor, col_src);

    dim3 gg((N_NODES + 127) / 128, 2);
    // layer 1
    k_gemm_dual<<<gg, 256, 0, stream>>>(x, Wl1, bl1, Wr1, br1, bufA, bufB, F_IN);
    k_edge<<<(N_NODES + 3) / 4, 256, 0, stream>>>(bufA, bufB, att1, b1, offsets, col_src, bufC);
    // layer 2
    k_gemm_dual<<<gg, 256, 0, stream>>>(bufC, Wl2, bl2, Wr2, br2, bufA, bufB, H_DIM);
    k_edge<<<(N_NODES + 3) / 4, 256, 0, stream>>>(bufA, bufB, att2, b2, offsets, col_src, bufC);
    // pool + head
    k_pool<<<(N_NODES + 127) / 128, 128, 0, stream>>>(bufC, batch, psum, pcnt);
    k_head<<<(N_GRAPH + 3) / 4, 256, 0, stream>>>(psum, pcnt, Wlin, blin, out);
}